// Round 1
// baseline (153.169 us; speedup 1.0000x reference)
//
#include <hip/hip_runtime.h>

// PointMassModel: X' = [v, a - g, c*(u - a)], RK4 x 8 substeps, h = DT/8.
// Linear constant-coefficient ODE => RK4 step is exactly the affine map
//   s+ = P s + Q w,  P = sum_{k=0..4} (hA)^k / k!,  Q = h * sum_{k=0..3} (hA)^k/(k+1)!
// 8 substeps compose to s8 = P^8 s0 + (I+P)(I+P^2)(I+P^4) Q w, w = E u + F g.
// Coefficients computed host-side in double; kernel is a pure streaming op.

#define ENVS_PER_BLOCK 256
#define THREADS 256

struct Coeffs {
    float P00, P01, P02;
    float P10, P11, P12;
    float P20, P21, P22;
    float Ku0, Ku1, Ku2;   // R[:,2] * c   (u coefficient)
    float Kg0, Kg1, Kg2;   // -R[:,1]      (g coefficient)
};

__global__ __launch_bounds__(THREADS)
void pointmass_kernel(const float* __restrict__ X0,
                      const float* __restrict__ U,
                      float* __restrict__ Out,
                      int envTotal, Coeffs cf) {
    __shared__ float s_x[ENVS_PER_BLOCK * 9];   // 9216 B, reused for output
    __shared__ float s_u[ENVS_PER_BLOCK * 3];   // 3072 B

    const int t = threadIdx.x;
    const int blockBase = blockIdx.x * ENVS_PER_BLOCK;
    const int envsHere = min(ENVS_PER_BLOCK, envTotal - blockBase);

    if (envsHere == ENVS_PER_BLOCK) {
        // ---- fast path: fully coalesced float4 staging ----
        const float4* x4 = (const float4*)(X0 + (size_t)blockBase * 9);
        const float4* u4 = (const float4*)(U  + (size_t)blockBase * 3);
        float4* o4 = (float4*)(Out + (size_t)blockBase * 9);

        #pragma unroll
        for (int j = t; j < ENVS_PER_BLOCK * 9 / 4; j += THREADS)   // 576 float4
            ((float4*)s_x)[j] = x4[j];
        if (t < ENVS_PER_BLOCK * 3 / 4)                              // 192 float4
            ((float4*)s_u)[t] = u4[t];
        __syncthreads();

        // per-thread env: stride-9-word LDS access = 2-way bank aliasing (free)
        float r[9];
        #pragma unroll
        for (int k = 0; k < 3; ++k) {
            const float p = s_x[t * 9 + k];
            const float v = s_x[t * 9 + 3 + k];
            const float a = s_x[t * 9 + 6 + k];
            const float u = s_u[t * 3 + k];
            const float g = (k == 2) ? -9.81f : 0.0f;
            r[k]     = cf.P00 * p + cf.P01 * v + cf.P02 * a + cf.Ku0 * u + cf.Kg0 * g;
            r[3 + k] = cf.P10 * p + cf.P11 * v + cf.P12 * a + cf.Ku1 * u + cf.Kg1 * g;
            r[6 + k] = cf.P20 * p + cf.P21 * v + cf.P22 * a + cf.Ku2 * u + cf.Kg2 * g;
        }
        // thread writes only its own 9 slots; sync before cooperative store
        #pragma unroll
        for (int i = 0; i < 9; ++i) s_x[t * 9 + i] = r[i];
        __syncthreads();

        #pragma unroll
        for (int j = t; j < ENVS_PER_BLOCK * 9 / 4; j += THREADS)
            o4[j] = ((const float4*)s_x)[j];
    } else {
        // ---- tail path (unused for N=2^21 but safe) ----
        for (int j = t; j < envsHere * 9; j += THREADS)
            s_x[j] = X0[(size_t)blockBase * 9 + j];
        for (int j = t; j < envsHere * 3; j += THREADS)
            s_u[j] = U[(size_t)blockBase * 3 + j];
        __syncthreads();
        if (t < envsHere) {
            float r[9];
            #pragma unroll
            for (int k = 0; k < 3; ++k) {
                const float p = s_x[t * 9 + k];
                const float v = s_x[t * 9 + 3 + k];
                const float a = s_x[t * 9 + 6 + k];
                const float u = s_u[t * 3 + k];
                const float g = (k == 2) ? -9.81f : 0.0f;
                r[k]     = cf.P00 * p + cf.P01 * v + cf.P02 * a + cf.Ku0 * u + cf.Kg0 * g;
                r[3 + k] = cf.P10 * p + cf.P11 * v + cf.P12 * a + cf.Ku1 * u + cf.Kg1 * g;
                r[6 + k] = cf.P20 * p + cf.P21 * v + cf.P22 * a + cf.Ku2 * u + cf.Kg2 * g;
            }
            #pragma unroll
            for (int i = 0; i < 9; ++i)
                Out[((size_t)blockBase + t) * 9 + i] = r[i];
        }
    }
}

// ---------------- host-side coefficient computation ----------------
static void mat3_mul(const double A[3][3], const double B[3][3], double C[3][3]) {
    for (int i = 0; i < 3; ++i)
        for (int j = 0; j < 3; ++j) {
            double s = 0.0;
            for (int k = 0; k < 3; ++k) s += A[i][k] * B[k][j];
            C[i][j] = s;
        }
}
static void mat3_copy(const double A[3][3], double B[3][3]) {
    for (int i = 0; i < 3; ++i) for (int j = 0; j < 3; ++j) B[i][j] = A[i][j];
}

extern "C" void kernel_launch(void* const* d_in, const int* in_sizes, int n_in,
                              void* d_out, int out_size, void* d_ws, size_t ws_size,
                              hipStream_t stream) {
    const float* X0 = (const float*)d_in[0];
    const float* U  = (const float*)d_in[1];
    float* Out = (float*)d_out;
    const int envTotal = in_sizes[0] / 9;

    // --- build RK4 closed-form coefficients in double ---
    const double DT = 0.02;
    const double h = DT / 8.0;
    const double c = 0.5 / DT;                 // LMBDA / DT = 25
    double hA[3][3] = {{0, h, 0}, {0, 0, h}, {0, 0, -c * h}};

    double hA2[3][3], hA3[3][3], hA4[3][3];
    mat3_mul(hA, hA, hA2);
    mat3_mul(hA2, hA, hA3);
    mat3_mul(hA3, hA, hA4);

    double P[3][3], Q[3][3];
    for (int i = 0; i < 3; ++i)
        for (int j = 0; j < 3; ++j) {
            const double I = (i == j) ? 1.0 : 0.0;
            P[i][j] = I + hA[i][j] + hA2[i][j] / 2.0 + hA3[i][j] / 6.0 + hA4[i][j] / 24.0;
            Q[i][j] = h * (I + hA[i][j] / 2.0 + hA2[i][j] / 6.0 + hA3[i][j] / 24.0);
        }

    double P2[3][3], P4[3][3], P8[3][3];
    mat3_mul(P, P, P2);
    mat3_mul(P2, P2, P4);
    mat3_mul(P4, P4, P8);

    // S = I + P + ... + P^7 = (I+P)(I+P^2)(I+P^4)
    double IP[3][3], IP2[3][3], IP4[3][3], T[3][3], S[3][3], R[3][3];
    mat3_copy(P, IP);  mat3_copy(P2, IP2);  mat3_copy(P4, IP4);
    for (int i = 0; i < 3; ++i) { IP[i][i] += 1.0; IP2[i][i] += 1.0; IP4[i][i] += 1.0; }
    mat3_mul(IP, IP2, T);
    mat3_mul(T, IP4, S);
    mat3_mul(S, Q, R);

    Coeffs cf;
    cf.P00 = (float)P8[0][0]; cf.P01 = (float)P8[0][1]; cf.P02 = (float)P8[0][2];
    cf.P10 = (float)P8[1][0]; cf.P11 = (float)P8[1][1]; cf.P12 = (float)P8[1][2];
    cf.P20 = (float)P8[2][0]; cf.P21 = (float)P8[2][1]; cf.P22 = (float)P8[2][2];
    cf.Ku0 = (float)(R[0][2] * c); cf.Ku1 = (float)(R[1][2] * c); cf.Ku2 = (float)(R[2][2] * c);
    cf.Kg0 = (float)(-R[0][1]);    cf.Kg1 = (float)(-R[1][1]);    cf.Kg2 = (float)(-R[2][1]);

    const int blocks = (envTotal + ENVS_PER_BLOCK - 1) / ENVS_PER_BLOCK;
    pointmass_kernel<<<blocks, THREADS, 0, stream>>>(X0, U, Out, envTotal, cf);
}